// Round 1
// baseline (407.179 us; speedup 1.0000x reference)
//
#include <hip/hip_runtime.h>
#include <hip/hip_bf16.h>
#include <math.h>

#define NROWS 131072
#define NCOLS 360               // 90 float4 per row
#define ROWS_PER_WAVE 8
#define NWAVES (NROWS / ROWS_PER_WAVE)      // 16384
#define NBLOCKS (NWAVES / 4)                // 4096

typedef float f32x4 __attribute__((ext_vector_type(4)));

// One wave per row, 8 rows per wave, processed in PAIRS so the two rows'
// shuffle-reduction chains (the latency-bound part) interleave. Row = 90
// float4: lane i holds f4[i], lanes 0..25 also f4[64+i]. Single streaming
// read of preds; no max-subtraction (|x|/sum|x| in [-1,1]); native exp/log;
// label value pulled from registers via shuffle.
// NOTE: 4-wide interleave was tried (R5) and regressed +3.8us — VGPR
// pressure outweighs extra ILP; 2-wide is the measured sweet spot.
// This round: (1) software-pipeline the pair loads (issue pair r+2's loads
// before pair r's shuffle spine — one pair of latency hiding for +16 VGPR),
// (2) fuse the final reduction via last-block-done so the second kernel
// launch (+grid drain before it) disappears. Final-reduce arithmetic is
// bit-identical to the old viewpoint_final_kernel (same order, same
// combine), so absmax is unchanged.
__global__ __launch_bounds__(256) void viewpoint_fused_kernel(
    const float* __restrict__ preds,
    const int* __restrict__ labels,
    float* __restrict__ partial,
    unsigned int* __restrict__ counter,
    float* __restrict__ out)
{
    const int wave = threadIdx.x >> 6;
    const int lane = threadIdx.x & 63;
    const int wgid = blockIdx.x * 4 + wave;            // 0..NWAVES-1
    const bool have2 = lane < (90 - 64);               // lanes 0..25

    float gacc = 0.f;

    // ---- preload pair 0 ----
    const f32x4* pA = (const f32x4*)(preds + (size_t)(0 * NWAVES + wgid) * NCOLS);
    const f32x4* pB = (const f32x4*)(preds + (size_t)(1 * NWAVES + wgid) * NCOLS);
    f32x4 a0 = __builtin_nontemporal_load(pA + lane);
    f32x4 b0 = __builtin_nontemporal_load(pB + lane);
    f32x4 a1 = {0.f, 0.f, 0.f, 0.f};
    f32x4 b1 = {0.f, 0.f, 0.f, 0.f};
    if (have2) {
        a1 = __builtin_nontemporal_load(pA + 64 + lane);
        b1 = __builtin_nontemporal_load(pB + 64 + lane);
    }

    #pragma unroll
    for (int r = 0; r < ROWS_PER_WAVE; r += 2) {
        const int rowA = r * NWAVES + wgid;
        const int rowB = (r + 1) * NWAVES + wgid;

        // ---- issue NEXT pair's loads before this pair's reduction spine ----
        f32x4 na0 = {0.f, 0.f, 0.f, 0.f}, nb0 = {0.f, 0.f, 0.f, 0.f};
        f32x4 na1 = {0.f, 0.f, 0.f, 0.f}, nb1 = {0.f, 0.f, 0.f, 0.f};
        if (r + 2 < ROWS_PER_WAVE) {
            const f32x4* nA = (const f32x4*)(preds + (size_t)((r + 2) * NWAVES + wgid) * NCOLS);
            const f32x4* nB = (const f32x4*)(preds + (size_t)((r + 3) * NWAVES + wgid) * NCOLS);
            na0 = __builtin_nontemporal_load(nA + lane);
            nb0 = __builtin_nontemporal_load(nB + lane);
            if (have2) {
                na1 = __builtin_nontemporal_load(nA + 64 + lane);
                nb1 = __builtin_nontemporal_load(nB + 64 + lane);
            }
        }

        // ---- per-lane sum |x| for both rows (abs folds into VOP3 mods) ----
        float sA = (fabsf(a0.x) + fabsf(a0.y)) + (fabsf(a0.z) + fabsf(a0.w))
                 + ((fabsf(a1.x) + fabsf(a1.y)) + (fabsf(a1.z) + fabsf(a1.w)));
        float sB = (fabsf(b0.x) + fabsf(b0.y)) + (fabsf(b0.z) + fabsf(b0.w))
                 + ((fabsf(b1.x) + fabsf(b1.y)) + (fabsf(b1.z) + fabsf(b1.w)));

        // interleaved butterflies — two independent chains
        #pragma unroll
        for (int off = 32; off > 0; off >>= 1) {
            sA += __shfl_xor(sA, off);
            sB += __shfl_xor(sB, off);
        }

        const float invA = __builtin_amdgcn_rcpf(sA);
        const float invB = __builtin_amdgcn_rcpf(sB);

        // ---- sum exp(x * inv); args bounded in [-1,1], no max needed ----
        float eA = (__expf(a0.x * invA) + __expf(a0.y * invA))
                 + (__expf(a0.z * invA) + __expf(a0.w * invA));
        float eB = (__expf(b0.x * invB) + __expf(b0.y * invB))
                 + (__expf(b0.z * invB) + __expf(b0.w * invB));
        if (have2) {
            eA += (__expf(a1.x * invA) + __expf(a1.y * invA))
                + (__expf(a1.z * invA) + __expf(a1.w * invA));
            eB += (__expf(b1.x * invB) + __expf(b1.y * invB))
                + (__expf(b1.z * invB) + __expf(b1.w * invB));
        }
        #pragma unroll
        for (int off = 32; off > 0; off >>= 1) {
            eA += __shfl_xor(eA, off);
            eB += __shfl_xor(eB, off);
        }

        // ---- x[label] from registers (labels[row] is wave-uniform) ----
        {
            const int lab = labels[rowA];
            const int f4i = lab >> 2, c = lab & 3;
            const f32x4 src = (f4i < 64) ? a0 : a1;
            const int owner = (f4i < 64) ? f4i : (f4i - 64);
            const float v = (c == 0) ? src.x : (c == 1) ? src.y
                          : (c == 2) ? src.z : src.w;
            gacc += __shfl(v, owner) * invA - __logf(eA);
        }
        {
            const int lab = labels[rowB];
            const int f4i = lab >> 2, c = lab & 3;
            const f32x4 src = (f4i < 64) ? b0 : b1;
            const int owner = (f4i < 64) ? f4i : (f4i - 64);
            const float v = (c == 0) ? src.x : (c == 1) ? src.y
                          : (c == 2) ? src.z : src.w;
            gacc += __shfl(v, owner) * invB - __logf(eB);
        }

        // rotate pipeline registers
        a0 = na0; a1 = na1; b0 = nb0; b1 = nb1;
    }

    // ---- per-block partial ----
    __shared__ float sh[4];
    __shared__ bool amLast;
    if (lane == 0) sh[wave] = gacc;
    __syncthreads();
    if (threadIdx.x == 0) {
        partial[blockIdx.x] = sh[0] + sh[1] + sh[2] + sh[3];
        __threadfence();                                   // release partial
        const unsigned int prev = atomicAdd(counter, 1u);  // device scope
        amLast = (prev == (unsigned int)(NBLOCKS - 1));
    }
    __syncthreads();

    // ---- last block: final reduction (bit-identical to old final kernel) ----
    if (amLast) {
        __threadfence();                                   // acquire partials
        const int n4 = NBLOCKS / 4;
        float s = 0.f;
        for (int i = threadIdx.x; i < n4; i += 256) {
            // volatile scalar loads, combined exactly like the old float4 path
            volatile const float* pp = partial + (size_t)i * 4;
            const float x = pp[0], y = pp[1], z = pp[2], w = pp[3];
            s += (x + y) + (z + w);
        }
        #pragma unroll
        for (int off = 32; off > 0; off >>= 1) s += __shfl_xor(s, off);
        __shared__ float sh2[4];
        if (lane == 0) sh2[wave] = s;
        __syncthreads();
        if (threadIdx.x == 0)
            out[0] = -(sh2[0] + sh2[1] + sh2[2] + sh2[3]) * (1.0f / (float)NCOLS);
    }
}

extern "C" void kernel_launch(void* const* d_in, const int* in_sizes, int n_in,
                              void* d_out, int out_size, void* d_ws, size_t ws_size,
                              hipStream_t stream) {
    const float* preds  = (const float*)d_in[0];
    const int*   labels = (const int*)d_in[1];
    float* out = (float*)d_out;
    float* partial = (float*)d_ws;                               // 4096 floats = 16 KB
    unsigned int* counter = (unsigned int*)((char*)d_ws + NBLOCKS * sizeof(float));

    // zero the last-block counter (graph-capture-legal memset node)
    hipMemsetAsync(counter, 0, sizeof(unsigned int), stream);

    viewpoint_fused_kernel<<<NBLOCKS, 256, 0, stream>>>(preds, labels, partial, counter, out);
}

// Round 4
// 249.390 us; speedup vs baseline: 1.6327x; 1.6327x over previous
//
#include <hip/hip_runtime.h>
#include <hip/hip_bf16.h>
#include <math.h>

#define NROWS 131072
#define NCOLS 360               // 90 float4 per row
#define ROWS_PER_WAVE 8
#define NWAVES (NROWS / ROWS_PER_WAVE)      // 16384
#define NBLOCKS (NWAVES / 4)                // 4096

typedef float f32x4 __attribute__((ext_vector_type(4)));

// One wave per row, 8 rows per wave, processed in PAIRS so the two rows'
// shuffle-reduction chains (the latency-bound part) interleave. Row = 90
// float4: lane i holds f4[i], lanes 0..25 also f4[64+i]. Single streaming
// read of preds; no max-subtraction (|x|/sum|x| in [-1,1]); native exp/log;
// label value pulled from registers via shuffle.
// NOTE (R5, prev session): 4-wide interleave regressed +3.8us — VGPR
// pressure outweighs extra ILP; 2-wide is the measured sweet spot.
// NOTE (R1, this session): last-block fusion with __threadfence regressed
// +160us — device-scope release fence = per-XCD L2 writeback/invalidate
// (buffer_wbl2/inv sc1) executed 4096x (512 per XCD). Counter evidence:
// kernel 165us with HBM 7%, VALU 12%, no spills. DO NOT reintroduce
// per-block device fences. Two-kernel structure is the safe shape.
// KEPT from R1: next-pair load prefetch (counter-exonerated: VGPR 40,
// zero scratch traffic) — one guaranteed pair of load-latency hiding.
// (R2/R3 were GPUAcquisitionTimeouts — this source has never run; resubmitted.)
__global__ __launch_bounds__(256) void viewpoint_row_kernel(
    const float* __restrict__ preds,
    const int* __restrict__ labels,
    float* __restrict__ partial)
{
    const int wave = threadIdx.x >> 6;
    const int lane = threadIdx.x & 63;
    const int wgid = blockIdx.x * 4 + wave;            // 0..NWAVES-1
    const bool have2 = lane < (90 - 64);               // lanes 0..25

    float gacc = 0.f;

    // ---- preload pair 0 ----
    const f32x4* pA = (const f32x4*)(preds + (size_t)(0 * NWAVES + wgid) * NCOLS);
    const f32x4* pB = (const f32x4*)(preds + (size_t)(1 * NWAVES + wgid) * NCOLS);
    f32x4 a0 = __builtin_nontemporal_load(pA + lane);
    f32x4 b0 = __builtin_nontemporal_load(pB + lane);
    f32x4 a1 = {0.f, 0.f, 0.f, 0.f};
    f32x4 b1 = {0.f, 0.f, 0.f, 0.f};
    if (have2) {
        a1 = __builtin_nontemporal_load(pA + 64 + lane);
        b1 = __builtin_nontemporal_load(pB + 64 + lane);
    }

    #pragma unroll
    for (int r = 0; r < ROWS_PER_WAVE; r += 2) {
        const int rowA = r * NWAVES + wgid;
        const int rowB = (r + 1) * NWAVES + wgid;

        // ---- issue NEXT pair's loads before this pair's reduction spine ----
        f32x4 na0 = {0.f, 0.f, 0.f, 0.f}, nb0 = {0.f, 0.f, 0.f, 0.f};
        f32x4 na1 = {0.f, 0.f, 0.f, 0.f}, nb1 = {0.f, 0.f, 0.f, 0.f};
        if (r + 2 < ROWS_PER_WAVE) {
            const f32x4* nA = (const f32x4*)(preds + (size_t)((r + 2) * NWAVES + wgid) * NCOLS);
            const f32x4* nB = (const f32x4*)(preds + (size_t)((r + 3) * NWAVES + wgid) * NCOLS);
            na0 = __builtin_nontemporal_load(nA + lane);
            nb0 = __builtin_nontemporal_load(nB + lane);
            if (have2) {
                na1 = __builtin_nontemporal_load(nA + 64 + lane);
                nb1 = __builtin_nontemporal_load(nB + 64 + lane);
            }
        }

        // ---- per-lane sum |x| for both rows (abs folds into VOP3 mods) ----
        float sA = (fabsf(a0.x) + fabsf(a0.y)) + (fabsf(a0.z) + fabsf(a0.w))
                 + ((fabsf(a1.x) + fabsf(a1.y)) + (fabsf(a1.z) + fabsf(a1.w)));
        float sB = (fabsf(b0.x) + fabsf(b0.y)) + (fabsf(b0.z) + fabsf(b0.w))
                 + ((fabsf(b1.x) + fabsf(b1.y)) + (fabsf(b1.z) + fabsf(b1.w)));

        // interleaved butterflies — two independent chains
        #pragma unroll
        for (int off = 32; off > 0; off >>= 1) {
            sA += __shfl_xor(sA, off);
            sB += __shfl_xor(sB, off);
        }

        const float invA = __builtin_amdgcn_rcpf(sA);
        const float invB = __builtin_amdgcn_rcpf(sB);

        // ---- sum exp(x * inv); args bounded in [-1,1], no max needed ----
        float eA = (__expf(a0.x * invA) + __expf(a0.y * invA))
                 + (__expf(a0.z * invA) + __expf(a0.w * invA));
        float eB = (__expf(b0.x * invB) + __expf(b0.y * invB))
                 + (__expf(b0.z * invB) + __expf(b0.w * invB));
        if (have2) {
            eA += (__expf(a1.x * invA) + __expf(a1.y * invA))
                + (__expf(a1.z * invA) + __expf(a1.w * invA));
            eB += (__expf(b1.x * invB) + __expf(b1.y * invB))
                + (__expf(b1.z * invB) + __expf(b1.w * invB));
        }
        #pragma unroll
        for (int off = 32; off > 0; off >>= 1) {
            eA += __shfl_xor(eA, off);
            eB += __shfl_xor(eB, off);
        }

        // ---- x[label] from registers (labels[row] is wave-uniform) ----
        {
            const int lab = labels[rowA];
            const int f4i = lab >> 2, c = lab & 3;
            const f32x4 src = (f4i < 64) ? a0 : a1;
            const int owner = (f4i < 64) ? f4i : (f4i - 64);
            const float v = (c == 0) ? src.x : (c == 1) ? src.y
                          : (c == 2) ? src.z : src.w;
            gacc += __shfl(v, owner) * invA - __logf(eA);
        }
        {
            const int lab = labels[rowB];
            const int f4i = lab >> 2, c = lab & 3;
            const f32x4 src = (f4i < 64) ? b0 : b1;
            const int owner = (f4i < 64) ? f4i : (f4i - 64);
            const float v = (c == 0) ? src.x : (c == 1) ? src.y
                          : (c == 2) ? src.z : src.w;
            gacc += __shfl(v, owner) * invB - __logf(eB);
        }

        // rotate pipeline registers
        a0 = na0; a1 = na1; b0 = nb0; b1 = nb1;
    }

    __shared__ float sh[4];
    if (lane == 0) sh[wave] = gacc;
    __syncthreads();
    if (threadIdx.x == 0)
        partial[blockIdx.x] = sh[0] + sh[1] + sh[2] + sh[3];
}

// Single-block final reduction of 4096 per-block partials (float4 loads).
__global__ __launch_bounds__(256) void viewpoint_final_kernel(
    const float* __restrict__ partial, float* __restrict__ out, int n4)
{
    const f32x4* p4 = (const f32x4*)partial;
    float s = 0.f;
    for (int i = threadIdx.x; i < n4; i += 256) {
        f32x4 v = p4[i];
        s += (v.x + v.y) + (v.z + v.w);
    }
    #pragma unroll
    for (int off = 32; off > 0; off >>= 1) s += __shfl_xor(s, off);
    __shared__ float sh[4];
    if ((threadIdx.x & 63) == 0) sh[threadIdx.x >> 6] = s;
    __syncthreads();
    if (threadIdx.x == 0)
        out[0] = -(sh[0] + sh[1] + sh[2] + sh[3]) * (1.0f / (float)NCOLS);
}

extern "C" void kernel_launch(void* const* d_in, const int* in_sizes, int n_in,
                              void* d_out, int out_size, void* d_ws, size_t ws_size,
                              hipStream_t stream) {
    const float* preds  = (const float*)d_in[0];
    const int*   labels = (const int*)d_in[1];
    float* out = (float*)d_out;
    float* partial = (float*)d_ws;                      // 4096 floats = 16 KB

    viewpoint_row_kernel<<<NBLOCKS, 256, 0, stream>>>(preds, labels, partial);
    viewpoint_final_kernel<<<1, 256, 0, stream>>>(partial, out, NBLOCKS / 4);
}